// Round 3
// baseline (4359.742 us; speedup 1.0000x reference)
//
#include <hip/hip_runtime.h>
#include <stdint.h>

#define IN    64
#define H     1024
#define G4    4096      // 4*H gate rows
#define BATCH 128
#define SEQ   256
#define TLEN  96
#define KCAT  1088      // IN + H
#define NSTEP (SEQ + TLEN)
#define NBLK  256

typedef __attribute__((ext_vector_type(8))) short bf16x8;
typedef __attribute__((ext_vector_type(4))) float f32x4;

__device__ __forceinline__ unsigned short f2bf(float f) {
  union { float f; uint32_t u; } v; v.f = f;
  uint32_t u = v.u;
  return (unsigned short)((u + 0x7fffu + ((u >> 16) & 1u)) >> 16);  // RNE
}

// fast tanh via hardware exp: max abs err ~1e-7, far below bf16 rounding.
__device__ __forceinline__ float fast_tanh(float x) {
  float ax = fabsf(x);
  float e  = __expf(-2.f * ax);
  float r  = (1.f - e) / (1.f + e);
  return copysignf(r, x);
}

// global->LDS direct copy, 16B/lane, aux=1 (SC0: bypass L1 so same-XCD L2 dirty
// lines from other CUs are observed). LDS dest = wave-uniform base + lane*16.
__device__ __forceinline__ void gload_lds16_sc0(const unsigned short* g, unsigned short* l) {
  __builtin_amdgcn_global_load_lds((const __attribute__((address_space(1))) unsigned int*)g,
                                   (__attribute__((address_space(3))) unsigned int*)l, 16, 0, 1);
}

// ---------- generic fp32 -> bf16 ----------
__global__ void k_convert(const float* __restrict__ src, unsigned short* __restrict__ dst, int n) {
  int i = blockIdx.x * blockDim.x + threadIdx.x;
  int stride = gridDim.x * blockDim.x;
  for (; i < n; i += stride) dst[i] = f2bf(src[i]);
}

// ---------- pack [Wih | Whh] gate-interleaved: packed row p=4j+g <-> torch row r=g*H+j ----------
__global__ void k_pack(const float* __restrict__ Wih, const float* __restrict__ Whh,
                       const float* __restrict__ bih, const float* __restrict__ bhh,
                       unsigned short* __restrict__ Wcat, float* __restrict__ bcat) {
  int p = blockIdx.x;                    // 0..4095
  int j = p >> 2, g = p & 3;
  int r = g * H + j;
  for (int c = threadIdx.x; c < KCAT; c += blockDim.x) {
    float v = (c < IN) ? Wih[r * IN + c] : Whh[r * H + (c - IN)];
    Wcat[(size_t)p * KCAT + c] = f2bf(v);
  }
  if (threadIdx.x == 0) bcat[p] = bih[r] + bhh[r];
}

// ---------- decoder fused weights: W_eff = Whh + Wih@lin ; b_eff = bih+bhh+Wih@lin_b ----------
__global__ void k_deceff(const float* __restrict__ Wih, const float* __restrict__ Whh,
                         const float* __restrict__ bih, const float* __restrict__ bhh,
                         const float* __restrict__ lin, const float* __restrict__ linb,
                         unsigned short* __restrict__ Weff, float* __restrict__ beff) {
  int p = blockIdx.x;
  int j = p >> 2, g = p & 3;
  int r = g * H + j;
  __shared__ float wr[IN];
  if (threadIdx.x < IN) wr[threadIdx.x] = Wih[r * IN + threadIdx.x];
  __syncthreads();
  for (int k = threadIdx.x; k < H; k += blockDim.x) {
    float acc = Whh[(size_t)r * H + k];
    #pragma unroll 8
    for (int i = 0; i < IN; ++i) acc += wr[i] * lin[(size_t)i * H + k];
    Weff[(size_t)p * H + k] = f2bf(acc);
  }
  if (threadIdx.x == 0) {
    float s = bih[r] + bhh[r];
    for (int i = 0; i < IN; ++i) s += wr[i] * linb[i];
    beff[p] = s;
  }
}

// ---------- persistent LSTM: XCD-local groups, weights in registers ----------
// Delta vs the 3984us passing kernel: the monolithic 32-block gather barrier is
// replaced by per-slice producer-consumer flags. flags[g][s] = "h produced at
// iteration t by block (g,s) is visible in L2" (value t+1). Each wave waits on
// the 4 flags of its 4 assigned slices and stages each 1KB slice as it becomes
// ready, so staging overlaps the straggler instead of serializing after it.
// Deadlock-free without a backward barrier: before (g,s) overwrites buffer A
// with h(t+2) it must have staged ALL of h(t+1), which implies every block
// finished consuming h(t) from buffer A (drift bounded at 2 steps).
// Flag primitive is byte-for-byte the proven one (relaxed agent-scope atomic
// store/load + s_sleep(1)); stores drained by __syncthreads before the flag.
// LDS h layout is slice-major [32][chunk(4)][row(16)][16B]: one global_load_lds
// per slice (per-lane global addr row=lane&15, chunk=lane>>4; linear LDS dest),
// frag reads hs[s*512 + fku*128 + fm*8] are phase-conflict-free.
// NOTE: dynamic-LDS request stays 86016 B on purpose: >80KB clamps occupancy
// to 1 block/CU, which pigeonholes exactly 32 blocks per XCD -- the ticket
// scheme REQUIRES that distribution (33/31 split would deadlock).
__global__ __launch_bounds__(512, 2) void k_lstm(
    const unsigned short* __restrict__ xin,
    const unsigned short* __restrict__ Wenc,  const float* __restrict__ benc,
    const unsigned short* __restrict__ Wdec0, const float* __restrict__ bdec0,
    const unsigned short* __restrict__ Wdeff, const float* __restrict__ bdeff,
    unsigned short* __restrict__ hbuf, unsigned short* __restrict__ hhist,
    unsigned int* __restrict__ flags, unsigned int* __restrict__ tickets)
{
  extern __shared__ char smem[];
  unsigned short* hs = (unsigned short*)smem;              // 32 slices x 1024 B = 32768 B
  __shared__ unsigned short ht[16][40];                    // h transpose staging (+pad)
  __shared__ int s_xcd, s_slot;
  const int tid  = threadIdx.x;
  const int lane = tid & 63;
  const int wave = tid >> 6;             // 0..7
  if (tid == 0) {
    unsigned x;
    asm volatile("s_getreg_b32 %0, hwreg(HW_REG_XCC_ID)" : "=s"(x));
    x &= 7;
    unsigned tk = __hip_atomic_fetch_add(&tickets[x], 1u, __ATOMIC_RELAXED, __HIP_MEMORY_SCOPE_AGENT);
    s_xcd = (int)x; s_slot = (int)(tk & 31);
  }
  __syncthreads();
  const int grp  = s_xcd;                // row-group == physical XCD
  const int slot = s_slot;               // col slot 0..31
  const int m0   = grp * 16;             // batch rows
  const int gw   = slot * 128 + wave * 16;   // this wave's 16 packed gate rows
  const int fm   = lane & 15;            // frag non-K index (gate row / batch row)
  const int fku  = lane >> 4;            // 0..3
  const int fk   = fku * 8;              // frag K offset
  const int unit = slot * 32 + wave * 4 + fku;   // h-unit this lane owns (0..1023)
  const int hrow = tid >> 5;             // store phase: batch row 0..15
  const int hcol = tid & 31;             // store phase: unit-local col 0..31
  unsigned int* gflags = flags + (size_t)grp * 32;   // packed: 32 x 4B = 128 B

  bf16x8 B[34];                          // [0..31] h-part K-tiles, [32..33] x-part
  float4 bias4;
  float cst = 0.f;
  int p = 0;
  for (int t = 0; t < NSTEP; ++t) {
    const bool is_enc = (t < SEQ);
    // ---- rare uniform weight (re)loads into registers ----
    if (t == 0 || t == SEQ) {
      const unsigned short* W = (t == 0) ? Wenc : Wdec0;
      const unsigned short* wr = W + (size_t)(gw + fm) * KCAT + fk;
      #pragma unroll
      for (int kt = 0; kt < 32; ++kt) B[kt] = *(const bf16x8*)(wr + IN + kt * 32);
      B[32] = *(const bf16x8*)(wr);
      B[33] = *(const bf16x8*)(wr + 32);
    } else if (t == SEQ + 1) {
      const unsigned short* wr = Wdeff + (size_t)(gw + fm) * H + fk;
      #pragma unroll
      for (int kt = 0; kt < 32; ++kt) B[kt] = *(const bf16x8*)(wr + kt * 32);
    }
    if (t == 0 || t == SEQ || t == SEQ + 1) {
      const float* bptr = (t == 0) ? benc : (t == SEQ ? bdec0 : bdeff);
      bias4 = *(const float4*)&bptr[4 * unit];   // i,f,g,o biases of this lane's unit
    }
    // ---- x fragments preloaded to registers (latency hides under flag waits) ----
    const bool hasx = is_enc || (t == SEQ);
    bf16x8 xa0, xa1;
    if (hasx) {
      const unsigned short* xsrc = xin + (size_t)(is_enc ? t : SEQ - 1) * BATCH * IN;
      const unsigned short* xa = xsrc + (size_t)(m0 + fm) * IN + fk;
      xa0 = *(const bf16x8*)(xa);
      xa1 = *(const bf16x8*)(xa + 32);
    }
    // ---- per-slice staging: wave w waits + stages slices 4w..4w+3 as ready ----
    if (t > 0) {
      const unsigned short* hb = hbuf + (size_t)p * BATCH * H + (size_t)m0 * H;
      #pragma unroll
      for (int j = 0; j < 4; ++j) {
        const int s = wave * 4 + j;
        while (__hip_atomic_load(&gflags[s], __ATOMIC_RELAXED, __HIP_MEMORY_SCOPE_AGENT) < (unsigned)t)
          __builtin_amdgcn_s_sleep(1);
        // slice s: rows m0..m0+15, units s*32..s*32+31 -> LDS [s][chunk=lane>>4][row=lane&15][16B]
        gload_lds16_sc0(hb + (size_t)fm * H + s * 32 + fk, &hs[s * 512]);
      }
    }
    __syncthreads();   // all 32 slices staged (vmcnt drained before s_barrier)
    // ---- K-loop, operand-swapped: D = W(A) * h(B) = z^T, two acc chains ----
    f32x4 acc0 = {0.f, 0.f, 0.f, 0.f};
    f32x4 acc1 = {0.f, 0.f, 0.f, 0.f};
    if (t > 0) {
      const unsigned short* as = &hs[fku * 128 + fm * 8];
      #pragma unroll
      for (int kt = 0; kt < 32; kt += 2) {
        acc0 = __builtin_amdgcn_mfma_f32_16x16x32_bf16(B[kt],     *(const bf16x8*)(as + kt * 512),       acc0, 0, 0, 0);
        acc1 = __builtin_amdgcn_mfma_f32_16x16x32_bf16(B[kt + 1], *(const bf16x8*)(as + kt * 512 + 512), acc1, 0, 0, 0);
      }
    }
    if (hasx) {
      acc0 = __builtin_amdgcn_mfma_f32_16x16x32_bf16(B[32], xa0, acc0, 0, 0, 0);
      acc1 = __builtin_amdgcn_mfma_f32_16x16x32_bf16(B[33], xa1, acc1, 0, 0, 0);
    }
    // ---- fused LSTM cell, fully lane-local: D row = 4*unit_local + gate, col = batch row ----
    {
      float zi = acc0[0] + acc1[0] + bias4.x;
      float zf = acc0[1] + acc1[1] + bias4.y;
      float zg = acc0[2] + acc1[2] + bias4.z;
      float zo = acc0[3] + acc1[3] + bias4.w;
      float gi = 1.f / (1.f + __expf(-zi));
      float gf = 1.f / (1.f + __expf(-zf));
      float gg = fast_tanh(zg);
      float go = 1.f / (1.f + __expf(-zo));
      float c  = gf * cst + gi * gg;
      cst = c;
      float h = go * fast_tanh(c);
      ht[fm][(wave << 2) + fku] = f2bf(h);   // tiny LDS transpose for coalesced store
    }
    __syncthreads();
    // ---- coalesced global h store: 32 consecutive tids write one 64B line ----
    {
      unsigned short hv = ht[hrow][hcol];
      size_t idx = (size_t)(m0 + hrow) * H + (size_t)slot * 32 + hcol;
      hbuf[(size_t)(1 - p) * BATCH * H + idx] = hv;            // plain store -> XCD L2
      if (!is_enc) hhist[(size_t)(t - SEQ) * BATCH * H + idx] = hv;
    }
    p ^= 1;
    // ---- publish: drain all waves' h stores into L2, then set this slot's flag ----
    if (t + 1 < NSTEP) {
      __syncthreads();
      if (tid == 0)
        __hip_atomic_store(&gflags[slot], (unsigned)(t + 1),
                           __ATOMIC_RELAXED, __HIP_MEMORY_SCOPE_AGENT);
    }
  }
}

// ---------- epilogue: all 96 outputs in one GEMM  y = hhist @ lin^T + lin_b ----------
__global__ __launch_bounds__(256) void k_out(
    const unsigned short* __restrict__ hhist, const unsigned short* __restrict__ linb16,
    const float* __restrict__ linb, float* __restrict__ out)
{
  const int tid  = threadIdx.x;
  const int lane = tid & 63;
  const int wave = tid >> 6;
  const int fm   = lane & 15;
  const int fk   = (lane >> 4) * 8;
  const int R0   = blockIdx.x * 64 + wave * 16;
  f32x4 acc[4] = {{0.f,0.f,0.f,0.f},{0.f,0.f,0.f,0.f},{0.f,0.f,0.f,0.f},{0.f,0.f,0.f,0.f}};
  const unsigned short* ha = hhist + (size_t)(R0 + fm) * H + fk;
  #pragma unroll 2
  for (int kc = 0; kc < H; kc += 32) {
    bf16x8 a = *(const bf16x8*)(ha + kc);
    #pragma unroll
    for (int nq = 0; nq < 4; ++nq) {
      bf16x8 b = *(const bf16x8*)(linb16 + (size_t)(nq * 16 + fm) * H + fk + kc);
      acc[nq] = __builtin_amdgcn_mfma_f32_16x16x32_bf16(a, b, acc[nq], 0, 0, 0);
    }
  }
  #pragma unroll
  for (int nq = 0; nq < 4; ++nq) {
    int col = nq * 16 + fm;
    float bb = linb[col];
    #pragma unroll
    for (int j = 0; j < 4; ++j) {
      int R = R0 + (lane >> 4) * 4 + j;
      out[(size_t)R * IN + col] = acc[nq][j] + bb;
    }
  }
}

extern "C" void kernel_launch(void* const* d_in, const int* in_sizes, int n_in,
                              void* d_out, int out_size, void* d_ws, size_t ws_size,
                              hipStream_t stream) {
  const float* input_batch = (const float*)d_in[0];
  // d_in[1] target_batch: unused (no teacher forcing)
  const float* eWih = (const float*)d_in[2];
  const float* eWhh = (const float*)d_in[3];
  const float* ebih = (const float*)d_in[4];
  const float* ebhh = (const float*)d_in[5];
  const float* dWih = (const float*)d_in[6];
  const float* dWhh = (const float*)d_in[7];
  const float* dbih = (const float*)d_in[8];
  const float* dbhh = (const float*)d_in[9];
  const float* linW = (const float*)d_in[10];
  const float* linb = (const float*)d_in[11];
  float* out = (float*)d_out;

  char* ws = (char*)d_ws;
  size_t off = 0;
  auto alloc = [&](size_t bytes) -> void* {
    void* pp = ws + off;
    off = (off + bytes + 255) & ~(size_t)255;
    return pp;
  };
  unsigned short* xin   = (unsigned short*)alloc((size_t)SEQ * BATCH * IN * 2);
  unsigned short* Wenc  = (unsigned short*)alloc((size_t)G4 * KCAT * 2);
  float*          benc  = (float*)         alloc((size_t)G4 * 4);
  unsigned short* Wdec0 = (unsigned short*)alloc((size_t)G4 * KCAT * 2);
  float*          bdec0 = (float*)         alloc((size_t)G4 * 4);
  unsigned short* Wdeff = (unsigned short*)alloc((size_t)G4 * H * 2);
  float*          bdeff = (float*)         alloc((size_t)G4 * 4);
  unsigned short* linbf = (unsigned short*)alloc((size_t)IN * H * 2);
  unsigned short* hbuf  = (unsigned short*)alloc((size_t)2 * BATCH * H * 2);
  unsigned short* hhist = (unsigned short*)alloc((size_t)TLEN * BATCH * H * 2);
  unsigned int*   flags = (unsigned int*)  alloc((size_t)8 * 32 * sizeof(unsigned));
  unsigned int*   tickets = (unsigned int*)alloc((size_t)8 * sizeof(unsigned));
  (void)ws_size; (void)in_sizes; (void)n_in; (void)out_size;

  hipMemsetAsync(flags, 0, (size_t)8 * 32 * sizeof(unsigned), stream);
  hipMemsetAsync(tickets, 0, (size_t)8 * sizeof(unsigned), stream);
  hipLaunchKernelGGL(k_convert, dim3(512), dim3(256), 0, stream, input_batch, xin, SEQ * BATCH * IN);
  hipLaunchKernelGGL(k_convert, dim3(64),  dim3(256), 0, stream, linW, linbf, IN * H);
  hipLaunchKernelGGL(k_pack,   dim3(G4), dim3(256), 0, stream, eWih, eWhh, ebih, ebhh, Wenc, benc);
  hipLaunchKernelGGL(k_pack,   dim3(G4), dim3(256), 0, stream, dWih, dWhh, dbih, dbhh, Wdec0, bdec0);
  hipLaunchKernelGGL(k_deceff, dim3(G4), dim3(256), 0, stream, dWih, dWhh, dbih, dbhh, linW, linb, Wdeff, bdeff);

  void* args[] = { &xin, &Wenc, &benc, &Wdec0, &bdec0, &Wdeff, &bdeff, &hbuf, &hhist, &flags, &tickets };
  hipLaunchCooperativeKernel((void*)k_lstm, dim3(NBLK), dim3(512), args, 86016, stream);

  hipLaunchKernelGGL(k_out, dim3((TLEN * BATCH) / 64), dim3(256), 0, stream, hhist, linbf, linb, out);
}

// Round 5
// 4077.148 us; speedup vs baseline: 1.0693x; 1.0693x over previous
//
#include <hip/hip_runtime.h>
#include <stdint.h>

#define IN    64
#define H     1024
#define G4    4096      // 4*H gate rows
#define BATCH 128
#define SEQ   256
#define TLEN  96
#define KCAT  1088      // IN + H
#define NSTEP (SEQ + TLEN)
#define NBLK  256
#define HPAD  1032      // h row stride in LDS (bf16), +8 pad

typedef __attribute__((ext_vector_type(8))) short bf16x8;
typedef __attribute__((ext_vector_type(4))) float f32x4;

__device__ __forceinline__ unsigned short f2bf(float f) {
  union { float f; uint32_t u; } v; v.f = f;
  uint32_t u = v.u;
  return (unsigned short)((u + 0x7fffu + ((u >> 16) & 1u)) >> 16);  // RNE
}

// fast tanh via hardware exp: max abs err ~1e-7, far below bf16 rounding.
__device__ __forceinline__ float fast_tanh(float x) {
  float ax = fabsf(x);
  float e  = __expf(-2.f * ax);
  float r  = (1.f - e) / (1.f + e);
  return copysignf(r, x);
}

// global->LDS direct copy, 16B/lane, aux=1 (SC0: bypass L1 so same-XCD L2 dirty
// lines from other CUs are observed). LDS dest = wave-uniform base + lane*16.
__device__ __forceinline__ void gload_lds16_sc0(const unsigned short* g, unsigned short* l) {
  __builtin_amdgcn_global_load_lds((const __attribute__((address_space(1))) unsigned int*)g,
                                   (__attribute__((address_space(3))) unsigned int*)l, 16, 0, 1);
}

// ---------- generic fp32 -> bf16 ----------
__global__ void k_convert(const float* __restrict__ src, unsigned short* __restrict__ dst, int n) {
  int i = blockIdx.x * blockDim.x + threadIdx.x;
  int stride = gridDim.x * blockDim.x;
  for (; i < n; i += stride) dst[i] = f2bf(src[i]);
}

// ---------- pack [Wih | Whh] gate-interleaved: packed row p=4j+g <-> torch row r=g*H+j ----------
__global__ void k_pack(const float* __restrict__ Wih, const float* __restrict__ Whh,
                       const float* __restrict__ bih, const float* __restrict__ bhh,
                       unsigned short* __restrict__ Wcat, float* __restrict__ bcat) {
  int p = blockIdx.x;                    // 0..4095
  int j = p >> 2, g = p & 3;
  int r = g * H + j;
  for (int c = threadIdx.x; c < KCAT; c += blockDim.x) {
    float v = (c < IN) ? Wih[r * IN + c] : Whh[r * H + (c - IN)];
    Wcat[(size_t)p * KCAT + c] = f2bf(v);
  }
  if (threadIdx.x == 0) bcat[p] = bih[r] + bhh[r];
}

// ---------- decoder fused weights: W_eff = Whh + Wih@lin ; b_eff = bih+bhh+Wih@lin_b ----------
__global__ void k_deceff(const float* __restrict__ Wih, const float* __restrict__ Whh,
                         const float* __restrict__ bih, const float* __restrict__ bhh,
                         const float* __restrict__ lin, const float* __restrict__ linb,
                         unsigned short* __restrict__ Weff, float* __restrict__ beff) {
  int p = blockIdx.x;
  int j = p >> 2, g = p & 3;
  int r = g * H + j;
  __shared__ float wr[IN];
  if (threadIdx.x < IN) wr[threadIdx.x] = Wih[r * IN + threadIdx.x];
  __syncthreads();
  for (int k = threadIdx.x; k < H; k += blockDim.x) {
    float acc = Whh[(size_t)r * H + k];
    #pragma unroll 8
    for (int i = 0; i < IN; ++i) acc += wr[i] * lin[(size_t)i * H + k];
    Weff[(size_t)p * H + k] = f2bf(acc);
  }
  if (threadIdx.x == 0) {
    float s = bih[r] + bhh[r];
    for (int i = 0; i < IN; ++i) s += wr[i] * linb[i];
    beff[p] = s;
  }
}

// ---------- persistent LSTM: XCD-local groups, weights in registers ----------
// Structure = the proven 3837us R2 kernel. SINGLE risky delta this round: the
// epoch barrier is a MONOTONIC COUNTER, not 32 per-slot flags. Block publishes
// iteration t via ONE agent-scope fetch_add(+1); ONE lane polls ctr >= 32*(t+1).
// Correct & deadlock-free: each block adds exactly once per iteration, so
// sum <= 32*(t+1) with equality iff every block published iteration t; a block
// cannot publish t+1 without first passing the t-poll => threshold exact,
// no reset needed, skew bounded at 1 (double-buffer argument unchanged).
// Why: the old scheme put 32 partial-line agent stores + ~32x32-lane polls on
// ONE MALL cacheline per step -- the hot-line service time is the prime suspect
// for the ~8us/step gap between measured (10.9us) and modeled (~2us) step time
// (R2 FETCH counters show ~9 MALL poll-fetch rounds per block per step).
// Same-address atomic RMWs pipeline at the MALL atomic unit; poll traffic
// drops 64x. Primitive family unchanged (HIP agent-scope atomics + s_sleep
// backoff -- the sc0 inline-asm flags from R0/R4 are blacklisted: 2/2 hangs).
// Low-risk carries proven in R3: fast_tanh, x-fragment preload.
// NOTE: dynamic-LDS request stays 86016 B on purpose: >80KB clamps occupancy
// to 1 block/CU, which pigeonholes exactly 32 blocks per XCD -- the ticket
// scheme REQUIRES that distribution (33/31 split would deadlock).
__global__ __launch_bounds__(512, 2) void k_lstm(
    const unsigned short* __restrict__ xin,
    const unsigned short* __restrict__ Wenc,  const float* __restrict__ benc,
    const unsigned short* __restrict__ Wdec0, const float* __restrict__ bdec0,
    const unsigned short* __restrict__ Wdeff, const float* __restrict__ bdeff,
    unsigned short* __restrict__ hbuf, unsigned short* __restrict__ hhist,
    unsigned int* __restrict__ flags, unsigned int* __restrict__ tickets)
{
  extern __shared__ char smem[];
  unsigned short* hs = (unsigned short*)smem;              // 16 x HPAD bf16 = 33024 B
  __shared__ unsigned short ht[16][40];                    // h transpose staging (+pad)
  __shared__ int s_xcd, s_slot;
  const int tid  = threadIdx.x;
  const int lane = tid & 63;
  const int wave = tid >> 6;             // 0..7
  if (tid == 0) {
    unsigned x;
    asm volatile("s_getreg_b32 %0, hwreg(HW_REG_XCC_ID)" : "=s"(x));
    x &= 7;
    unsigned tk = __hip_atomic_fetch_add(&tickets[x], 1u, __ATOMIC_RELAXED, __HIP_MEMORY_SCOPE_AGENT);
    s_xcd = (int)x; s_slot = (int)(tk & 31);
  }
  __syncthreads();
  const int grp  = s_xcd;                // row-group == physical XCD
  const int slot = s_slot;               // col slot 0..31
  const int m0   = grp * 16;             // batch rows
  const int gw   = slot * 128 + wave * 16;   // this wave's 16 packed gate rows
  const int fm   = lane & 15;            // frag non-K index (gate row / batch row)
  const int fku  = lane >> 4;            // 0..3
  const int fk   = fku * 8;              // frag K offset
  const int unit = slot * 32 + wave * 4 + fku;   // h-unit this lane owns (0..1023)
  const int hrow = tid >> 5;             // store phase: batch row 0..15
  const int hcol = tid & 31;             // store phase: unit-local col 0..31
  unsigned int* gctr = flags + (size_t)grp * 32;   // ONE counter per group, 128B apart

  bf16x8 B[34];                          // [0..31] h-part K-tiles, [32..33] x-part
  float4 bias4;
  float cst = 0.f;
  int p = 0;
  for (int t = 0; t < NSTEP; ++t) {
    const bool is_enc = (t < SEQ);
    // ---- rare uniform weight (re)loads into registers ----
    if (t == 0 || t == SEQ) {
      const unsigned short* W = (t == 0) ? Wenc : Wdec0;
      const unsigned short* wr = W + (size_t)(gw + fm) * KCAT + fk;
      #pragma unroll
      for (int kt = 0; kt < 32; ++kt) B[kt] = *(const bf16x8*)(wr + IN + kt * 32);
      B[32] = *(const bf16x8*)(wr);
      B[33] = *(const bf16x8*)(wr + 32);
    } else if (t == SEQ + 1) {
      const unsigned short* wr = Wdeff + (size_t)(gw + fm) * H + fk;
      #pragma unroll
      for (int kt = 0; kt < 32; ++kt) B[kt] = *(const bf16x8*)(wr + kt * 32);
    }
    if (t == 0 || t == SEQ || t == SEQ + 1) {
      const float* bptr = (t == 0) ? benc : (t == SEQ ? bdec0 : bdeff);
      bias4 = *(const float4*)&bptr[4 * unit];   // i,f,g,o biases of this lane's unit
    }
    // ---- x fragments preloaded to registers ----
    const bool hasx = is_enc || (t == SEQ);
    bf16x8 xa0, xa1;
    if (hasx) {
      const unsigned short* xsrc = xin + (size_t)(is_enc ? t : SEQ - 1) * BATCH * IN;
      const unsigned short* xa = xsrc + (size_t)(m0 + fm) * IN + fk;
      xa0 = *(const bf16x8*)(xa);
      xa1 = *(const bf16x8*)(xa + 32);
    }
    // ---- stage h(t) rows (16 x 1024 bf16 = 32 KB) from XCD L2 into LDS ----
    if (t > 0) {
      const unsigned short* hb = hbuf + (size_t)p * BATCH * H + (size_t)m0 * H;
      #pragma unroll
      for (int j = 0; j < 4; ++j) {
        int row  = wave * 2 + (j >> 1);
        int half = (j & 1) * 512;
        gload_lds16_sc0(hb + (size_t)row * H + half + lane * 8, &hs[row * HPAD + half]);
      }
    }
    __syncthreads();   // staging complete (vmcnt drained before s_barrier)
    // ---- K-loop, operand-swapped: D = W(A) * h(B) = z^T, two acc chains ----
    f32x4 acc0 = {0.f, 0.f, 0.f, 0.f};
    f32x4 acc1 = {0.f, 0.f, 0.f, 0.f};
    if (t > 0) {
      const unsigned short* as = &hs[fm * HPAD + fk];
      #pragma unroll
      for (int kt = 0; kt < 32; kt += 2) {
        acc0 = __builtin_amdgcn_mfma_f32_16x16x32_bf16(B[kt],     *(const bf16x8*)(as + kt * 32),      acc0, 0, 0, 0);
        acc1 = __builtin_amdgcn_mfma_f32_16x16x32_bf16(B[kt + 1], *(const bf16x8*)(as + kt * 32 + 32), acc1, 0, 0, 0);
      }
    }
    if (hasx) {
      acc0 = __builtin_amdgcn_mfma_f32_16x16x32_bf16(B[32], xa0, acc0, 0, 0, 0);
      acc1 = __builtin_amdgcn_mfma_f32_16x16x32_bf16(B[33], xa1, acc1, 0, 0, 0);
    }
    // ---- fused LSTM cell, fully lane-local: D row = 4*unit_local + gate, col = batch row ----
    {
      float zi = acc0[0] + acc1[0] + bias4.x;
      float zf = acc0[1] + acc1[1] + bias4.y;
      float zg = acc0[2] + acc1[2] + bias4.z;
      float zo = acc0[3] + acc1[3] + bias4.w;
      float gi = 1.f / (1.f + __expf(-zi));
      float gf = 1.f / (1.f + __expf(-zf));
      float gg = fast_tanh(zg);
      float go = 1.f / (1.f + __expf(-zo));
      float c  = gf * cst + gi * gg;
      cst = c;
      float h = go * fast_tanh(c);
      ht[fm][(wave << 2) + fku] = f2bf(h);   // tiny LDS transpose for coalesced store
    }
    __syncthreads();
    // ---- coalesced global h store: 32 consecutive tids write one 64B line ----
    {
      unsigned short hv = ht[hrow][hcol];
      size_t idx = (size_t)(m0 + hrow) * H + (size_t)slot * 32 + hcol;
      hbuf[(size_t)(1 - p) * BATCH * H + idx] = hv;            // plain store -> XCD L2
      if (!is_enc) hhist[(size_t)(t - SEQ) * BATCH * H + idx] = hv;
    }
    p ^= 1;
    // ---- XCD-local epoch barrier: monotonic counter, 1 add + 1-lane poll ----
    if (t + 1 < NSTEP) {
      __syncthreads();   // drains all waves' h stores into L2 before publish
      if (tid == 0) {
        __hip_atomic_fetch_add(gctr, 1u, __ATOMIC_RELAXED, __HIP_MEMORY_SCOPE_AGENT);
        while (__hip_atomic_load(gctr, __ATOMIC_RELAXED, __HIP_MEMORY_SCOPE_AGENT)
               < 32u * (unsigned)(t + 1))
          __builtin_amdgcn_s_sleep(1);
      }
      __syncthreads();
    }
  }
}

// ---------- epilogue: all 96 outputs in one GEMM  y = hhist @ lin^T + lin_b ----------
__global__ __launch_bounds__(256) void k_out(
    const unsigned short* __restrict__ hhist, const unsigned short* __restrict__ linb16,
    const float* __restrict__ linb, float* __restrict__ out)
{
  const int tid  = threadIdx.x;
  const int lane = tid & 63;
  const int wave = tid >> 6;
  const int fm   = lane & 15;
  const int fk   = (lane >> 4) * 8;
  const int R0   = blockIdx.x * 64 + wave * 16;
  f32x4 acc[4] = {{0.f,0.f,0.f,0.f},{0.f,0.f,0.f,0.f},{0.f,0.f,0.f,0.f},{0.f,0.f,0.f,0.f}};
  const unsigned short* ha = hhist + (size_t)(R0 + fm) * H + fk;
  #pragma unroll 2
  for (int kc = 0; kc < H; kc += 32) {
    bf16x8 a = *(const bf16x8*)(ha + kc);
    #pragma unroll
    for (int nq = 0; nq < 4; ++nq) {
      bf16x8 b = *(const bf16x8*)(linb16 + (size_t)(nq * 16 + fm) * H + fk + kc);
      acc[nq] = __builtin_amdgcn_mfma_f32_16x16x32_bf16(a, b, acc[nq], 0, 0, 0);
    }
  }
  #pragma unroll
  for (int nq = 0; nq < 4; ++nq) {
    int col = nq * 16 + fm;
    float bb = linb[col];
    #pragma unroll
    for (int j = 0; j < 4; ++j) {
      int R = R0 + (lane >> 4) * 4 + j;
      out[(size_t)R * IN + col] = acc[nq][j] + bb;
    }
  }
}

extern "C" void kernel_launch(void* const* d_in, const int* in_sizes, int n_in,
                              void* d_out, int out_size, void* d_ws, size_t ws_size,
                              hipStream_t stream) {
  const float* input_batch = (const float*)d_in[0];
  // d_in[1] target_batch: unused (no teacher forcing)
  const float* eWih = (const float*)d_in[2];
  const float* eWhh = (const float*)d_in[3];
  const float* ebih = (const float*)d_in[4];
  const float* ebhh = (const float*)d_in[5];
  const float* dWih = (const float*)d_in[6];
  const float* dWhh = (const float*)d_in[7];
  const float* dbih = (const float*)d_in[8];
  const float* dbhh = (const float*)d_in[9];
  const float* linW = (const float*)d_in[10];
  const float* linb = (const float*)d_in[11];
  float* out = (float*)d_out;

  char* ws = (char*)d_ws;
  size_t off = 0;
  auto alloc = [&](size_t bytes) -> void* {
    void* pp = ws + off;
    off = (off + bytes + 255) & ~(size_t)255;
    return pp;
  };
  unsigned short* xin   = (unsigned short*)alloc((size_t)SEQ * BATCH * IN * 2);
  unsigned short* Wenc  = (unsigned short*)alloc((size_t)G4 * KCAT * 2);
  float*          benc  = (float*)         alloc((size_t)G4 * 4);
  unsigned short* Wdec0 = (unsigned short*)alloc((size_t)G4 * KCAT * 2);
  float*          bdec0 = (float*)         alloc((size_t)G4 * 4);
  unsigned short* Wdeff = (unsigned short*)alloc((size_t)G4 * H * 2);
  float*          bdeff = (float*)         alloc((size_t)G4 * 4);
  unsigned short* linbf = (unsigned short*)alloc((size_t)IN * H * 2);
  unsigned short* hbuf  = (unsigned short*)alloc((size_t)2 * BATCH * H * 2);
  unsigned short* hhist = (unsigned short*)alloc((size_t)TLEN * BATCH * H * 2);
  unsigned int*   flags = (unsigned int*)  alloc((size_t)8 * 32 * sizeof(unsigned));
  unsigned int*   tickets = (unsigned int*)alloc((size_t)8 * sizeof(unsigned));
  (void)ws_size; (void)in_sizes; (void)n_in; (void)out_size;

  hipMemsetAsync(flags, 0, (size_t)8 * 32 * sizeof(unsigned), stream);
  hipMemsetAsync(tickets, 0, (size_t)8 * sizeof(unsigned), stream);
  hipLaunchKernelGGL(k_convert, dim3(512), dim3(256), 0, stream, input_batch, xin, SEQ * BATCH * IN);
  hipLaunchKernelGGL(k_convert, dim3(64),  dim3(256), 0, stream, linW, linbf, IN * H);
  hipLaunchKernelGGL(k_pack,   dim3(G4), dim3(256), 0, stream, eWih, eWhh, ebih, ebhh, Wenc, benc);
  hipLaunchKernelGGL(k_pack,   dim3(G4), dim3(256), 0, stream, dWih, dWhh, dbih, dbhh, Wdec0, bdec0);
  hipLaunchKernelGGL(k_deceff, dim3(G4), dim3(256), 0, stream, dWih, dWhh, dbih, dbhh, linW, linb, Wdeff, bdeff);

  void* args[] = { &xin, &Wenc, &benc, &Wdec0, &bdec0, &Wdeff, &bdeff, &hbuf, &hhist, &flags, &tickets };
  hipLaunchCooperativeKernel((void*)k_lstm, dim3(NBLK), dim3(512), args, 86016, stream);

  hipLaunchKernelGGL(k_out, dim3((TLEN * BATCH) / 64), dim3(256), 0, stream, hhist, linbf, linb, out);
}